// Round 11
// baseline (727.126 us; speedup 1.0000x reference)
//
#include <hip/hip_runtime.h>
#include <math.h>

// Capsule routing, u_hat never materialized (factors through W):
//   v[b,n,c] = sum_i c[b,n,i] u[b,i,c]
//   s[b,n,d] = sum_c v[b,n,c] W[c,n*64+d];  o = squash(s)
//   t[b,n,c] = sum_d o[b,n,d] W[c,n*64+d]
//   b[b,n,i] = sum_c t[b,n,c] u[b,i,c]
// Iter 0: b=0 -> c uniform 1/32 -> v0 = colsum(u)/32.
//
// R18 (2nd resubmit after two GPU-acquisition timeouts; kernel unchanged).
// LAUNCH-COUNT round, from probe arithmetic (R14: +2 route = +23us;
// R16: +6 mixed = +60us => ~10-11.5us per LAUNCH regardless of kernel;
// exec is 1-4us each). R13/R15/R17 were null because they optimized exec.
// R12's fence fusion failed; this one needs NO fences: everything after
// k_pre factors per-b, so ONE block per b runs the whole chain
//   sst0 -> route1 -> sst1 -> route2 -> sst2 -> out
// with all cross-itile reductions done in-block (pv accumulated in
// registers + LDS; pvb and tb16 global round-trips deleted entirely).
// 6 launches -> 2. Grid 32 x 1024 thr (4 teams x 4 waves); ~126KB LDS;
// route per team = verified k_route structure, 8 itiles sequentially;
// cross-team v-reduce = 4 barriered rounds (deterministic, no atomics).
// pv now accumulated fp32 (was bf16 via global) -> numerics equal/better.
// Carried: ub16+uT16+W precast (k_pre unchanged), no grid.sync, no fences.

constexpr int Bn = 32, In = 1024, Cn = 256, Nn = 32, Dn = 64, ND = 2048;

typedef __attribute__((ext_vector_type(8))) short bf16x8;
typedef __attribute__((ext_vector_type(4))) float f32x4;

__device__ __forceinline__ unsigned int packbf2(float a, float b) {
  unsigned int xa = __float_as_uint(a), xb = __float_as_uint(b);
  xa = (xa + 0x7fffu + ((xa >> 16) & 1u)) >> 16;  // RNE
  xb = (xb + 0x7fffu + ((xb >> 16) & 1u)) >> 16;
  return xa | (xb << 16);
}
__device__ __forceinline__ unsigned short packbf1(float a) {
  unsigned int x = __float_as_uint(a);
  return (unsigned short)((x + 0x7fffu + ((x >> 16) & 1u)) >> 16);
}
__device__ __forceinline__ float bfu(unsigned short us) {
  return __uint_as_float((unsigned int)us << 16);
}

// ---- k_pre: colsum + ucast + uT16 (z<1024) | WbfT (1024..1151) | Wbf cast --
__global__ __launch_bounds__(256) void k_pre(
    const float* __restrict__ u, const float* __restrict__ W,
    float* __restrict__ psu, unsigned short* __restrict__ Wbf,
    unsigned short* __restrict__ WbfT, unsigned short* __restrict__ ub16,
    unsigned short* __restrict__ uT16) {
  const int z = blockIdx.x, tid = threadIdx.x;
  if (z < 1024) {  // colsum: psu[z*256+c] = sum over 32 i of u[b, ch*32+i, c]
    int b = z >> 5, ch = z & 31;
    const float* up = u + ((size_t)(b * In + ch * 32)) * Cn + tid;
    unsigned short* ubp = ub16 + ((size_t)(b * In + ch * 32)) * Cn + tid;
    float s = 0.f;
    unsigned int q[16];
#pragma unroll
    for (int m = 0; m < 16; ++m) {
      float v0 = up[(size_t)(2 * m) * Cn];
      float v1 = up[(size_t)(2 * m + 1) * Cn];
      s += v0 + v1;
      ubp[(size_t)(2 * m) * Cn] = packbf1(v0);      // i-major bf16 copy
      ubp[(size_t)(2 * m + 1) * Cn] = packbf1(v1);
      q[m] = packbf2(v0, v1);                        // c-major pack
    }
    psu[(size_t)z * Cn + tid] = s;
    // uT16[b][c=tid][ch*32 .. +31]: 64 B contiguous per thread
    unsigned short* tp = uT16 + ((size_t)(b * Cn + tid)) * In + ch * 32;
    *(uint4*)&tp[0]  = make_uint4(q[0], q[1], q[2], q[3]);
    *(uint4*)&tp[8]  = make_uint4(q[4], q[5], q[6], q[7]);
    *(uint4*)&tp[16] = make_uint4(q[8], q[9], q[10], q[11]);
    *(uint4*)&tp[24] = make_uint4(q[12], q[13], q[14], q[15]);
  } else if (z < 1152) {  // WbfT[nd][c] = bf16(W[c][nd]), 64x64 tiles
    __shared__ float tile[64][65];
    int t = z - 1024;
    int x0 = (t & 31) * 64, y0 = (t >> 5) * 64;  // x=nd, y=c
    int lx = tid & 63, ly = tid >> 6;
#pragma unroll
    for (int k = 0; k < 16; ++k) {
      int y = ly + k * 4;
      tile[y][lx] = W[(size_t)(y0 + y) * ND + x0 + lx];
    }
    __syncthreads();
#pragma unroll
    for (int k = 0; k < 8; ++k) {  // 64 rows x 32 uints
      int idx = tid + k * 256;
      int row = idx >> 5, cu = idx & 31;
      unsigned int v = packbf2(tile[2 * cu][row], tile[2 * cu + 1][row]);
      *(unsigned int*)&WbfT[(size_t)(x0 + row) * Cn + y0 + 2 * cu] = v;
    }
  } else {  // Wbf: straight cast, 128 blocks x 4096 floats
    int zb = z - 1152;
    const float* src = W + (size_t)zb * 4096;
    unsigned short* dst = Wbf + (size_t)zb * 4096;
#pragma unroll
    for (int k = 0; k < 4; ++k) {
      int off = k * 1024 + tid * 4;
      const float4 v = *(const float4*)&src[off];
      *(uint2*)&dst[off] = make_uint2(packbf2(v.x, v.y), packbf2(v.z, v.w));
    }
  }
}

// ---- k_all: whole routing chain for one b in one block --------------------
// 1024 threads = 4 teams x 4 waves. Teams process itiles tm, tm+4, ..,tm+28.
__global__ __launch_bounds__(1024) void k_all(
    const float* __restrict__ psu, const unsigned short* __restrict__ ub16,
    const unsigned short* __restrict__ uT16,
    const unsigned short* __restrict__ Wbf,
    const unsigned short* __restrict__ WbfT, float* __restrict__ out) {
  const int b = blockIdx.x;
  const int tid = threadIdx.x;
  const int lane = tid & 63;
  const int tm = tid >> 8;               // team 0..3
  const int w = (tid >> 6) & 3;          // wave within team
  const int mrow = lane & 15, quad = lane >> 4;
  const int mt = w & 1, cb = w >> 1;     // route wave roles

  __shared__ unsigned short t_l[32][264];     // current t (bf16)
  __shared__ float v_acc[32][260];            // v accumulator (fp32)
  __shared__ float bb_t[4][32][36];           // per-team bb
  __shared__ float smr_t[4][2][8][32];        // per-team softmax scratch
  __shared__ unsigned short cm_t[4][32][40];  // per-team softmax(c) bf16
  __shared__ float sscr[4][2048];             // sst phase-2 partials
  __shared__ float ol[32][64];                // squash output o[n][d]
  __shared__ float v0s[256];                  // iter-0 uniform v

  // ---- v0 = colsum/32 from psu[b] ----
  {
    const int g = tid >> 8, c = tid & 255;
    const float* pp = psu + (size_t)b * 8192 + (size_t)(g * 8) * 256 + c;
    float a = 0.f;
#pragma unroll
    for (int k = 0; k < 8; ++k) a += pp[(size_t)k * 256];
    sscr[g][c] = a;
  }
  __syncthreads();
  if (tid < 256)
    v0s[tid] = (sscr[0][tid] + sscr[1][tid] + sscr[2][tid] + sscr[3][tid]) *
               (1.0f / 32.0f);
  __syncthreads();

  for (int itx = 0; itx < 3; ++itx) {
    const bool uniform = (itx == 0);
    const bool last = (itx == 2);

    // ---- sst: S2 s-partials ----
    {
      const int cg = tid >> 8, x = tid & 255, n = x >> 3, d8 = (x & 7) * 8;
      const unsigned short* wp = Wbf + (size_t)(cg * 64) * ND + n * Dn + d8;
      float acc[8];
#pragma unroll
      for (int e = 0; e < 8; ++e) acc[e] = 0.f;
#pragma unroll
      for (int c2 = 0; c2 < 64; ++c2) {
        union { bf16x8 v; unsigned short us[8]; } w8;
        w8.v = *(const bf16x8*)&wp[(size_t)c2 * ND];
        const float vc = uniform ? v0s[cg * 64 + c2] : v_acc[n][cg * 64 + c2];
#pragma unroll
        for (int e = 0; e < 8; ++e) acc[e] += vc * bfu(w8.us[e]);
      }
      *(float4*)&sscr[cg][n * 64 + d8] =
          make_float4(acc[0], acc[1], acc[2], acc[3]);
      *(float4*)&sscr[cg][n * 64 + d8 + 4] =
          make_float4(acc[4], acc[5], acc[6], acc[7]);
    }
    __syncthreads();
    // ---- sst: reduce + squash (16 waves x 2 n) ----
    {
      const int ww = tid >> 6;
#pragma unroll
      for (int half = 0; half < 2; ++half) {
        const int n = ww + half * 16;
        const int nd = n * 64 + lane;
        float s = sscr[0][nd] + sscr[1][nd] + sscr[2][nd] + sscr[3][nd];
        float sq = s * s;
#pragma unroll
        for (int off = 32; off > 0; off >>= 1) sq += __shfl_xor(sq, off, 64);
        float o = s / sqrtf(sq + 1e-7f);
        ol[n][lane] = o;
        if (last) out[((size_t)b * 32 + n) * 64 + lane] = o;
      }
    }
    __syncthreads();
    if (last) return;
    // ---- sst: S3 t_new[n][c] = sum_d o[n,d] WbfT[n*64+d][c] ----
    {
      const int n = tid >> 5, c8 = (tid & 31) * 8;
      const unsigned short* wt = WbfT + (size_t)(n * Dn) * Cn + c8;
      float acc[8];
#pragma unroll
      for (int e = 0; e < 8; ++e) acc[e] = 0.f;
#pragma unroll
      for (int d2 = 0; d2 < 64; ++d2) {
        union { bf16x8 v; unsigned short us[8]; } w8;
        w8.v = *(const bf16x8*)&wt[(size_t)d2 * Cn];
        const float od = ol[n][d2];
#pragma unroll
        for (int e = 0; e < 8; ++e) acc[e] += od * bfu(w8.us[e]);
      }
      *(uint2*)&t_l[n][c8] =
          make_uint2(packbf2(acc[0], acc[1]), packbf2(acc[2], acc[3]));
      *(uint2*)&t_l[n][c8 + 4] =
          make_uint2(packbf2(acc[4], acc[5]), packbf2(acc[6], acc[7]));
    }
    __syncthreads();

    // ---- route: 8 itiles per team, pv accumulated in vreg ----
    float vreg[32];
#pragma unroll
    for (int k = 0; k < 32; ++k) vreg[k] = 0.f;
    for (int r8 = 0; r8 < 8; ++r8) {
      const int i0 = (r8 * 4 + tm) * 32;
      // phase A: bb[i,n] = sum_c u[i,c] t[n,c]
      {
        const int i0t = mt * 16, n0t = cb * 16;
        const unsigned short* ubp =
            ub16 + ((size_t)(b * In + i0 + i0t + mrow)) * Cn + quad * 8;
        f32x4 acc = {0.f, 0.f, 0.f, 0.f};
#pragma unroll
        for (int k0 = 0; k0 < 8; ++k0) {
          const bf16x8 af = *(const bf16x8*)(ubp + k0 * 32);
          const bf16x8 bf =
              *(const bf16x8*)&t_l[n0t + mrow][k0 * 32 + quad * 8];
          acc = __builtin_amdgcn_mfma_f32_16x16x32_bf16(af, bf, acc, 0, 0, 0);
        }
#pragma unroll
        for (int r = 0; r < 4; ++r)
          bb_t[tm][n0t + mrow][i0t + quad * 4 + r] = acc[r];
      }
      __syncthreads();
      // softmax over n per i (team-local)
      {
        const int i = tid & 31, g5 = (tid >> 5) & 7;
        float m4 = fmaxf(fmaxf(bb_t[tm][g5 * 4 + 0][i], bb_t[tm][g5 * 4 + 1][i]),
                         fmaxf(bb_t[tm][g5 * 4 + 2][i], bb_t[tm][g5 * 4 + 3][i]));
        smr_t[tm][0][g5][i] = m4;
        __syncthreads();
        float m = smr_t[tm][0][0][i];
#pragma unroll
        for (int k = 1; k < 8; ++k) m = fmaxf(m, smr_t[tm][0][k][i]);
        float e[4];
        float s4 = 0.f;
#pragma unroll
        for (int r = 0; r < 4; ++r) {
          e[r] = __expf(bb_t[tm][g5 * 4 + r][i] - m);
          s4 += e[r];
        }
        smr_t[tm][1][g5][i] = s4;
        __syncthreads();
        float ss = 0.f;
#pragma unroll
        for (int k = 0; k < 8; ++k) ss += smr_t[tm][1][k][i];
        float inv = 1.f / ss;
#pragma unroll
        for (int r = 0; r < 4; ++r)
          cm_t[tm][g5 * 4 + r][i] = packbf1(e[r] * inv);
      }
      __syncthreads();
      // phase B: pv[n,c] += c.u for this itile (fp32, in registers)
      {
        const bf16x8 af = *(const bf16x8*)&cm_t[tm][mt * 16 + mrow][quad * 8];
        const unsigned short* utp =
            uT16 + ((size_t)(b * Cn + cb * 128 + mrow)) * In + i0 + quad * 8;
#pragma unroll
        for (int j = 0; j < 8; ++j) {
          const bf16x8 bfv = *(const bf16x8*)&utp[(size_t)(j * 16) * In];
          f32x4 d = {0.f, 0.f, 0.f, 0.f};
          d = __builtin_amdgcn_mfma_f32_16x16x32_bf16(af, bfv, d, 0, 0, 0);
          vreg[j * 4 + 0] += d[0];
          vreg[j * 4 + 1] += d[1];
          vreg[j * 4 + 2] += d[2];
          vreg[j * 4 + 3] += d[3];
        }
      }
      __syncthreads();
    }
    // ---- cross-team reduce into v_acc (4 deterministic rounds) ----
    for (int tm2 = 0; tm2 < 4; ++tm2) {
      if (tm == tm2) {
#pragma unroll
        for (int k = 0; k < 32; ++k) {
          const int n = mt * 16 + quad * 4 + (k & 3);
          const int c = (cb * 8 + (k >> 2)) * 16 + mrow;
          if (tm2 == 0) v_acc[n][c] = vreg[k];
          else v_acc[n][c] += vreg[k];
        }
      }
      __syncthreads();
    }
  }
}

extern "C" void kernel_launch(void* const* d_in, const int* in_sizes, int n_in,
                              void* d_out, int out_size, void* d_ws, size_t ws_size,
                              hipStream_t stream) {
  (void)in_sizes; (void)n_in; (void)out_size; (void)ws_size;
  const float* u = (const float*)d_in[0];   // (32,1024,256)
  const float* W = (const float*)d_in[1];   // (256,2048)
  float* out = (float*)d_out;               // (32,32,64)
  float* ws = (float*)d_ws;
  // ws layout (float units): [0..4194304) unused (was pvb) | psu 262144 |
  // Wbf 262144 | WbfT 262144 | unused (was tb16) | ub16 4194304 | uT16.
  float*          psu  = ws + 4194304;
  unsigned short* Wbf  = (unsigned short*)(ws + 4456448);
  unsigned short* WbfT = (unsigned short*)(ws + 4718592);
  unsigned short* ub16 = (unsigned short*)(ws + 5242880);
  unsigned short* uT16 = (unsigned short*)(ws + 9437184);

  k_pre<<<1280, 256, 0, stream>>>(u, W, psu, Wbf, WbfT, ub16, uT16);
  k_all<<<32, 1024, 0, stream>>>(psu, ub16, uT16, Wbf, WbfT, out);
}

// Round 12
// 126.260 us; speedup vs baseline: 5.7590x; 5.7590x over previous
//
#include <hip/hip_runtime.h>
#include <math.h>

// Capsule routing, u_hat never materialized (factors through W):
//   v[b,n,c] = sum_i c[b,n,i] u[b,i,c]
//   s[b,n,d] = sum_c v[b,n,c] W[c,n*64+d];  o = squash(s)
//   t[b,n,c] = sum_d o[b,n,d] W[c,n*64+d]
//   b[b,n,i] = sum_c t[b,n,c] u[b,i,c]
// Iter 0: b=0 -> c uniform 1/32 -> v0 = colsum(u)/32.
//
// R19: REVERT to R17 (verified 127.47us), after R18's fused k_all measured
// 646us (32 blocks = 12.5% of CUs, occupancy 6%, FETCH 198MB). Fusion
// ledger complete: R12 per-block fences +150us; R4 grid.sync +900us; R18
// single-block-per-b +600us. The 6-launch chain is the minimum for this
// dependency structure on gfx950. Session model (fits all rounds <0.5us):
//   dur = 67.4us harness-fixed + ~10us/launch x 6 + residual exec.
// R13/R15/R17 (three different kernel structures) all = 127.5 +- 0.1us:
// exec is sub-dominant; this is the structural floor.

constexpr int Bn = 32, In = 1024, Cn = 256, Nn = 32, Dn = 64, ND = 2048;

typedef __attribute__((ext_vector_type(8))) short bf16x8;
typedef __attribute__((ext_vector_type(4))) float f32x4;

__device__ __forceinline__ unsigned int packbf2(float a, float b) {
  unsigned int xa = __float_as_uint(a), xb = __float_as_uint(b);
  xa = (xa + 0x7fffu + ((xa >> 16) & 1u)) >> 16;  // RNE
  xb = (xb + 0x7fffu + ((xb >> 16) & 1u)) >> 16;
  return xa | (xb << 16);
}
__device__ __forceinline__ unsigned short packbf1(float a) {
  unsigned int x = __float_as_uint(a);
  return (unsigned short)((x + 0x7fffu + ((x >> 16) & 1u)) >> 16);
}
__device__ __forceinline__ float bfu(unsigned short us) {
  return __uint_as_float((unsigned int)us << 16);
}

// ---- k_pre: colsum + ucast + uT16 (z<1024) | WbfT (1024..1151) | Wbf cast --
__global__ __launch_bounds__(256) void k_pre(
    const float* __restrict__ u, const float* __restrict__ W,
    float* __restrict__ psu, unsigned short* __restrict__ Wbf,
    unsigned short* __restrict__ WbfT, unsigned short* __restrict__ ub16,
    unsigned short* __restrict__ uT16) {
  const int z = blockIdx.x, tid = threadIdx.x;
  if (z < 1024) {  // colsum: psu[z*256+c] = sum over 32 i of u[b, ch*32+i, c]
    int b = z >> 5, ch = z & 31;
    const float* up = u + ((size_t)(b * In + ch * 32)) * Cn + tid;
    unsigned short* ubp = ub16 + ((size_t)(b * In + ch * 32)) * Cn + tid;
    float s = 0.f;
    unsigned int q[16];
#pragma unroll
    for (int m = 0; m < 16; ++m) {
      float v0 = up[(size_t)(2 * m) * Cn];
      float v1 = up[(size_t)(2 * m + 1) * Cn];
      s += v0 + v1;
      ubp[(size_t)(2 * m) * Cn] = packbf1(v0);      // i-major bf16 copy
      ubp[(size_t)(2 * m + 1) * Cn] = packbf1(v1);
      q[m] = packbf2(v0, v1);                        // c-major pack
    }
    psu[(size_t)z * Cn + tid] = s;
    // uT16[b][c=tid][ch*32 .. +31]: 64 B contiguous per thread
    unsigned short* tp = uT16 + ((size_t)(b * Cn + tid)) * In + ch * 32;
    *(uint4*)&tp[0]  = make_uint4(q[0], q[1], q[2], q[3]);
    *(uint4*)&tp[8]  = make_uint4(q[4], q[5], q[6], q[7]);
    *(uint4*)&tp[16] = make_uint4(q[8], q[9], q[10], q[11]);
    *(uint4*)&tp[24] = make_uint4(q[12], q[13], q[14], q[15]);
  } else if (z < 1152) {  // WbfT[nd][c] = bf16(W[c][nd]), 64x64 tiles
    __shared__ float tile[64][65];
    int t = z - 1024;
    int x0 = (t & 31) * 64, y0 = (t >> 5) * 64;  // x=nd, y=c
    int lx = tid & 63, ly = tid >> 6;
#pragma unroll
    for (int k = 0; k < 16; ++k) {
      int y = ly + k * 4;
      tile[y][lx] = W[(size_t)(y0 + y) * ND + x0 + lx];
    }
    __syncthreads();
#pragma unroll
    for (int k = 0; k < 8; ++k) {  // 64 rows x 32 uints
      int idx = tid + k * 256;
      int row = idx >> 5, cu = idx & 31;
      unsigned int v = packbf2(tile[2 * cu][row], tile[2 * cu + 1][row]);
      *(unsigned int*)&WbfT[(size_t)(x0 + row) * Cn + y0 + 2 * cu] = v;
    }
  } else {  // Wbf: straight cast, 128 blocks x 4096 floats
    int zb = z - 1152;
    const float* src = W + (size_t)zb * 4096;
    unsigned short* dst = Wbf + (size_t)zb * 4096;
#pragma unroll
    for (int k = 0; k < 4; ++k) {
      int off = k * 1024 + tid * 4;
      const float4 v = *(const float4*)&src[off];
      *(uint2*)&dst[off] = make_uint2(packbf2(v.x, v.y), packbf2(v.z, v.w));
    }
  }
}

// ---- k_sst: 4-b-grouped. Block (n, bg) does b = bg*4..+3 for one n. -------
// W n-slices read once per block, reused across 4 b in registers.
__global__ __launch_bounds__(512) void k_sst(
    const void* __restrict__ src, int srcBf16, long bS, long nS, long cS,
    float scale, const unsigned short* __restrict__ Wbf,
    const unsigned short* __restrict__ WbfT, unsigned short* __restrict__ tb,
    float* __restrict__ outp, int writeT) {
  const int bx = blockIdx.x;
  const int n = bx & 31, bg = bx >> 5;  // same-n blocks share XCD (bx%8=n%8)
  const int tid = threadIdx.x;
  const int wid = tid >> 6, lane = tid & 63;
  __shared__ float vsh[4][256];   // v per bb
  __shared__ float pw[8][4][64];  // phase-2 partials [wave][bb][d]
  __shared__ float ol[4][64];     // squash output per bb
  __shared__ float pt[2][4][256]; // phase-3 partials [dg][bb][c]

  {  // v-reduce: team bb = tid>>7 handles its b; 2 c per thread, 32 it
    const int bb = tid >> 7, c0 = tid & 127;
    const long base = (long)(bg * 4 + bb) * bS + (long)n * nS;
    float a0 = 0.f, a1 = 0.f;
    if (srcBf16) {
      const unsigned short* p = (const unsigned short*)src + base;
#pragma unroll
      for (int it = 0; it < 32; ++it) {
        a0 += bfu(p[(size_t)it * cS + c0]);
        a1 += bfu(p[(size_t)it * cS + c0 + 128]);
      }
    } else {
      const float* p = (const float*)src + base;
#pragma unroll
      for (int it = 0; it < 32; ++it) {
        a0 += p[(size_t)it * cS + c0];
        a1 += p[(size_t)it * cS + c0 + 128];
      }
    }
    vsh[bb][c0] = a0 * scale;
    vsh[bb][c0 + 128] = a1 * scale;
  }
  __syncthreads();
  {  // phase 2: wave wid covers c in [wid*32,+32), lane = d; acc over 4 b
    const unsigned short* wp = Wbf + (size_t)(wid * 32) * ND + n * Dn + lane;
    float a0 = 0.f, a1 = 0.f, a2 = 0.f, a3 = 0.f;
#pragma unroll
    for (int j = 0; j < 32; ++j) {
      const float wval = bfu(wp[(size_t)j * ND]);   // read once, 4 b reuse
      const int c = wid * 32 + j;
      a0 += vsh[0][c] * wval;
      a1 += vsh[1][c] * wval;
      a2 += vsh[2][c] * wval;
      a3 += vsh[3][c] * wval;
    }
    pw[wid][0][lane] = a0; pw[wid][1][lane] = a1;
    pw[wid][2][lane] = a2; pw[wid][3][lane] = a3;
  }
  __syncthreads();
  if (tid < 256) {  // reduce + squash: one wave per bb (tid 0..63 -> bb0 ...)
    const int bb = tid >> 6, d = tid & 63;
    float a = 0.f;
#pragma unroll
    for (int k = 0; k < 8; ++k) a += pw[k][bb][d];
    float sq = a * a;
#pragma unroll
    for (int off = 32; off > 0; off >>= 1) sq += __shfl_xor(sq, off, 64);
    float o = a / sqrtf(sq + 1e-7f);
    ol[bb][d] = o;
    if (outp) outp[(size_t)((bg * 4 + bb) * 32 + n) * 64 + d] = o;
  }
  __syncthreads();
  if (writeT) {
    {  // phase 3 partials: thread (dg = tid>>8, c = tid&255), 32 d each
      const int dg = tid >> 8, c = tid & 255;
      const unsigned short* wt =
          WbfT + (size_t)(n * Dn + dg * 32) * Cn + c;
      float a0 = 0.f, a1 = 0.f, a2 = 0.f, a3 = 0.f;
#pragma unroll
      for (int d2 = 0; d2 < 32; ++d2) {
        const float wval = bfu(wt[(size_t)d2 * Cn]);  // read once, 4 b reuse
        const int d = dg * 32 + d2;
        a0 += ol[0][d] * wval;
        a1 += ol[1][d] * wval;
        a2 += ol[2][d] * wval;
        a3 += ol[3][d] * wval;
      }
      pt[dg][0][c] = a0; pt[dg][1][c] = a1;
      pt[dg][2][c] = a2; pt[dg][3][c] = a3;
    }
    __syncthreads();
    if (tid < 256) {
      const int c = tid;
#pragma unroll
      for (int bb = 0; bb < 4; ++bb) {
        float t = pt[0][bb][c] + pt[1][bb][c];
        tb[(size_t)((bg * 4 + bb) * 32 + n) * Cn + c] = packbf1(t);
      }
    }
  }
}

// ---- fused routing step (MFMA): bb = u.t^T -> softmax -> pv = c.u ----------
__global__ __launch_bounds__(256, 4) void k_route(
    const unsigned short* __restrict__ tbb,
    const unsigned short* __restrict__ ub16,
    const unsigned short* __restrict__ uT16,
    unsigned short* __restrict__ pvb) {
  const int b = blockIdx.x, itile = blockIdx.y, i0 = itile * 32;
  const int tid = threadIdx.x;
  const int lane = tid & 63, w = tid >> 6;
  const int mrow = lane & 15, quad = lane >> 4;

  __shared__ unsigned short t_l[32][264];   // bf16; row 528 B; reused as pvs
  __shared__ unsigned short cm_l[32][40];   // bf16 softmax(c)
  __shared__ float bb_l[32][36];
  __shared__ float smr[2][8][32];           // softmax partial max / sum

  // ---- stage t (straight bf16 copy) ----
  {
    const unsigned short* tp = tbb + (size_t)b * Nn * Cn;
#pragma unroll
    for (int k = 0; k < 8; ++k) {
      int idx = tid + k * 256;           // 2048 = 32 rows x 64 quads
      int row = idx >> 6, q = idx & 63;
      *(uint2*)&t_l[row][q * 4] = *(const uint2*)&tp[(size_t)row * Cn + q * 4];
    }
  }
  __syncthreads();

  // ---- phase A: D[i,n] = sum_c u[i,c] t[n,c]; wave tile (i0t, n0t) ----
  {
    const int i0t = (w & 1) * 16, n0t = (w >> 1) * 16;
    const unsigned short* ubp =
        ub16 + ((size_t)(b * In + i0 + i0t + mrow)) * Cn + quad * 8;
    f32x4 acc = {0.f, 0.f, 0.f, 0.f};
#pragma unroll
    for (int k0 = 0; k0 < 8; ++k0) {       // c = k0*32 + quad*8 + j
      const bf16x8 af = *(const bf16x8*)(ubp + k0 * 32);
      const bf16x8 bf = *(const bf16x8*)&t_l[n0t + mrow][k0 * 32 + quad * 8];
      acc = __builtin_amdgcn_mfma_f32_16x16x32_bf16(af, bf, acc, 0, 0, 0);
    }
    // D: col=lane&15 -> n within tile, row=quad*4+reg -> i within tile
#pragma unroll
    for (int r = 0; r < 4; ++r)
      bb_l[n0t + mrow][i0t + quad * 4 + r] = acc[r];
  }
  __syncthreads();

  // ---- softmax over n per i (wave-parallel), pack to cm_l fused in tail ---
  {
    const int i = tid & 31, g = tid >> 5;  // g handles n = g*4 .. g*4+3
    float m4 = fmaxf(fmaxf(bb_l[g * 4 + 0][i], bb_l[g * 4 + 1][i]),
                     fmaxf(bb_l[g * 4 + 2][i], bb_l[g * 4 + 3][i]));
    smr[0][g][i] = m4;
    __syncthreads();
    float m = smr[0][0][i];
#pragma unroll
    for (int k = 1; k < 8; ++k) m = fmaxf(m, smr[0][k][i]);
    float e[4];
    float s4 = 0.f;
#pragma unroll
    for (int r = 0; r < 4; ++r) {
      e[r] = __expf(bb_l[g * 4 + r][i] - m);
      s4 += e[r];
    }
    smr[1][g][i] = s4;
    __syncthreads();
    float ss = 0.f;
#pragma unroll
    for (int k = 0; k < 8; ++k) ss += smr[1][k][i];
    float inv = 1.f / ss;
#pragma unroll
    for (int r = 0; r < 4; ++r) cm_l[g * 4 + r][i] = packbf1(e[r] * inv);
  }
  __syncthreads();

  // ---- phase B: D[n,c] = sum_i c[n,i] u[i,c]; K=32 -> 1 MFMA/tile ----
  unsigned short* pvs = &t_l[0][0];
  {
    const int mt = w & 1;                  // ncap tile (0..1)
    const bf16x8 af = *(const bf16x8*)&cm_l[mt * 16 + mrow][quad * 8];
    // c = (w>>1)*128 + j*16 + mrow ; i = i0 + quad*8 + e
    const unsigned short* utp =
        uT16 + ((size_t)(b * Cn + (w >> 1) * 128 + mrow)) * In + i0 + quad * 8;
#pragma unroll
    for (int j = 0; j < 8; ++j) {
      const int ct = (w >> 1) * 8 + j;     // c tile (0..15)
      const bf16x8 bfv = *(const bf16x8*)&utp[(size_t)(j * 16) * In];
      f32x4 d = {0.f, 0.f, 0.f, 0.f};
      d = __builtin_amdgcn_mfma_f32_16x16x32_bf16(af, bfv, d, 0, 0, 0);
      // D: col=lane&15 -> c within tile, row=quad*4+reg -> ncap within tile
#pragma unroll
      for (int r = 0; r < 4; ++r)
        pvs[(size_t)(mt * 16 + quad * 4 + r) * 264 + ct * 16 + mrow] =
            packbf1(d[r]);
    }
  }
  __syncthreads();
  {  // coalesced pvb store: thread (rg=tid>>5, co=tid&31); rows rg+8k
    unsigned short* pb = pvb + (size_t)((b * 32 + itile) * Nn) * Cn;
    const int rg = tid >> 5, co = tid & 31;
#pragma unroll
    for (int k = 0; k < 4; ++k) {
      int row = rg + k * 8;
      const uint4 v = *(const uint4*)&pvs[(size_t)row * 264 + co * 8];
      *(uint4*)&pb[(size_t)row * Cn + co * 8] = v;
    }
  }
}

extern "C" void kernel_launch(void* const* d_in, const int* in_sizes, int n_in,
                              void* d_out, int out_size, void* d_ws, size_t ws_size,
                              hipStream_t stream) {
  (void)in_sizes; (void)n_in; (void)out_size; (void)ws_size;
  const float* u = (const float*)d_in[0];   // (32,1024,256)
  const float* W = (const float*)d_in[1];   // (256,2048)
  float* out = (float*)d_out;               // (32,32,64)
  float* ws = (float*)d_ws;
  // ws layout (float units): pvb bf16 4194304 | psu 262144 | Wbf 262144 |
  // WbfT 262144 | tb16 262144 | ub16 4194304 | uT16 4194304  => 52 MB.
  unsigned short* pvb  = (unsigned short*)ws;
  float*          psu  = ws + 4194304;
  unsigned short* Wbf  = (unsigned short*)(ws + 4456448);
  unsigned short* WbfT = (unsigned short*)(ws + 4718592);
  unsigned short* tb16 = (unsigned short*)(ws + 4980736);
  unsigned short* ub16 = (unsigned short*)(ws + 5242880);
  unsigned short* uT16 = (unsigned short*)(ws + 9437184);

  k_pre<<<1280, 256, 0, stream>>>(u, W, psu, Wbf, WbfT, ub16, uT16);
  // iter 0: v0 = colsum/32 (psu fp32: b-stride 8192, it(ch)-stride 256)
  k_sst<<<256, 512, 0, stream>>>(psu, 0, 8192L, 0L, 256L, 1.0f / 32.0f,
                                 Wbf, WbfT, tb16, nullptr, 1);
  // iter 1
  k_route<<<dim3(32, 32), 256, 0, stream>>>(tb16, ub16, uT16, pvb);
  // pvb bf16: b-stride 262144, n-stride 256, it-stride 8192 (ushort units)
  k_sst<<<256, 512, 0, stream>>>(pvb, 1, 262144L, 256L, 8192L, 1.0f,
                                 Wbf, WbfT, tb16, nullptr, 1);
  // iter 2 (final)
  k_route<<<dim3(32, 32), 256, 0, stream>>>(tb16, ub16, uT16, pvb);
  k_sst<<<256, 512, 0, stream>>>(pvb, 1, 262144L, 256L, 8192L, 1.0f,
                                 Wbf, WbfT, tb16, out, 0);
}